// Round 1
// baseline (203.282 us; speedup 1.0000x reference)
//
#include <hip/hip_runtime.h>
#include <utility>
#include <cstddef>

#define N_ATOMS 20000
#define N_EDGES 50000
#define FDIM 16
#define NPATHS 33

// ======================= compile-time CG table generation =======================
// Reproduces reference _cg / _umat / _real_cg exactly (double precision, cast to float).
namespace cgx {

constexpr double cfac(int n){ double r = 1.0; for (int i = 2; i <= n; ++i) r *= (double)i; return r; }

constexpr double csqrt(double x){
  if (x <= 0.0) return 0.0;
  double g = (x >= 1.0) ? x : 1.0;
  for (int i = 0; i < 200; ++i){
    double ng = 0.5 * (g + x / g);
    if (ng == g) break;
    g = ng;
  }
  return g;
}

constexpr double cg_coef(int j1,int m1,int j2,int m2,int j3,int m3){
  if (m1 + m2 != m3) return 0.0;
  int dlo = (j1 > j2) ? (j1 - j2) : (j2 - j1);
  if (j3 < dlo || j3 > j1 + j2) return 0.0;
  double pre = csqrt((2.0*j3+1.0) * cfac(j3+j1-j2) * cfac(j3-j1+j2) * cfac(j1+j2-j3) / cfac(j1+j2+j3+1));
  pre *= csqrt(cfac(j3+m3)*cfac(j3-m3)*cfac(j1-m1)*cfac(j1+m1)*cfac(j2-m2)*cfac(j2+m2));
  int kmin = 0;
  if (j2 - j3 - m1 > kmin) kmin = j2 - j3 - m1;
  if (j1 - j3 + m2 > kmin) kmin = j1 - j3 + m2;
  int kmax = j1 + j2 - j3;
  if (j1 - m1 < kmax) kmax = j1 - m1;
  if (j2 + m2 < kmax) kmax = j2 + m2;
  double s = 0.0;
  for (int k = kmin; k <= kmax; ++k){
    double t = 1.0 / (cfac(k)*cfac(j1+j2-j3-k)*cfac(j1-m1-k)*cfac(j2+m2-k)*cfac(j3-j2+m1+k)*cfac(j3-j1-m2+k));
    s += (k & 1) ? -t : t;
  }
  return pre * s;
}

struct Cplx { double re; double im; };
constexpr double S2C = 0.70710678118654752440;

// U[row, col] of the real<->complex transform (reference _umat)
constexpr Cplx u_entry(int l, int row, int col){
  int m = row - l;
  if (m > 0){
    if (col == m + l)  return Cplx{ (m & 1) ? -S2C : S2C, 0.0 };
    if (col == -m + l) return Cplx{ S2C, 0.0 };
  } else if (m == 0){
    if (col == l) return Cplx{ 1.0, 0.0 };
  } else {
    int am = -m;
    if (col == m + l)  return Cplx{ 0.0, S2C };
    if (col == am + l) return Cplx{ 0.0, (am & 1) ? S2C : -S2C };  // -i*(-1)^am*s2
  }
  return Cplx{ 0.0, 0.0 };
}

// Stage A: complex-basis CG values per path (m3 = m1+m2 fixed)
template<int L1,int L2,int L3>
struct CGCTab { double v[(2*L1+1)*(2*L2+1)]; };

template<int L1,int L2,int L3>
constexpr CGCTab<L1,L2,L3> make_cgc(){
  CGCTab<L1,L2,L3> t{};
  for (int A = 0; A < 2*L1+1; ++A){
    for (int B = 0; B < 2*L2+1; ++B){
      int MA = A - L1, MB = B - L2, MC = MA + MB;
      t.v[A*(2*L2+1)+B] = (MC < -L3 || MC > L3) ? 0.0 : cg_coef(L1,MA,L2,MB,L3,MC);
    }
  }
  return t;
}
template<int L1,int L2,int L3>
struct CGCH { static constexpr CGCTab<L1,L2,L3> t = make_cgc<L1,L2,L3>(); };

// Stage B: real-basis tensor G[a,b,c]  (reference _real_cg)
template<int L1,int L2,int L3>
struct GTab { float v[(2*L1+1)*(2*L2+1)*(2*L3+1)]; };

template<int L1,int L2,int L3>
constexpr GTab<L1,L2,L3> make_g(){
  GTab<L1,L2,L3> g{};
  constexpr int NA = 2*L1+1, NB = 2*L2+1, NC = 2*L3+1;
  for (int a = 0; a < NA; ++a){
    for (int b = 0; b < NB; ++b){
      for (int c = 0; c < NC; ++c){
        double re = 0.0, im = 0.0;
        for (int A = 0; A < NA; ++A){
          Cplx u1 = u_entry(L1, a, A);
          if (u1.re == 0.0 && u1.im == 0.0) continue;
          int MA = A - L1;
          for (int B = 0; B < NB; ++B){
            Cplx u2 = u_entry(L2, b, B);
            if (u2.re == 0.0 && u2.im == 0.0) continue;
            int MB = B - L2;
            int MC = MA + MB;
            if (MC < -L3 || MC > L3) continue;
            Cplx u3 = u_entry(L3, c, MC + L3);
            if (u3.re == 0.0 && u3.im == 0.0) continue;
            double cgv = CGCH<L1,L2,L3>::t.v[A*NB + B];
            if (cgv == 0.0) continue;
            u3.im = -u3.im;  // conj
            double pr = u1.re*u2.re - u1.im*u2.im;
            double pi_ = u1.re*u2.im + u1.im*u2.re;
            re += (pr*u3.re - pi_*u3.im) * cgv;
            im += (pr*u3.im + pi_*u3.re) * cgv;
          }
        }
        g.v[(a*NB + b)*NC + c] = (float)(((L1 + L2 + L3) % 2 == 0) ? re : im);
      }
    }
  }
  return g;
}
template<int L1,int L2,int L3>
struct GH { static constexpr GTab<L1,L2,L3> t = make_g<L1,L2,L3>(); };

struct PathD { int l1, l2, l3; };
// EXACT reference enumeration order (l1 outer, l2 mid, l3 = |l1-l2| .. min(l1+l2,4))
constexpr PathD PATHS_C[NPATHS] = {
  {0,0,0},{0,1,1},{0,2,2},{0,3,3},{0,4,4},
  {1,0,1},{1,1,0},{1,1,1},{1,1,2},{1,2,1},{1,2,2},{1,2,3},{1,3,2},{1,3,3},{1,3,4},{1,4,3},{1,4,4},
  {2,0,2},{2,1,1},{2,1,2},{2,1,3},{2,2,0},{2,2,1},{2,2,2},{2,2,3},{2,2,4},
  {2,3,1},{2,3,2},{2,3,3},{2,3,4},{2,4,2},{2,4,3},{2,4,4}
};

constexpr const float* G_PTRS[NPATHS] = {
  GH<0,0,0>::t.v, GH<0,1,1>::t.v, GH<0,2,2>::t.v, GH<0,3,3>::t.v, GH<0,4,4>::t.v,
  GH<1,0,1>::t.v, GH<1,1,0>::t.v, GH<1,1,1>::t.v, GH<1,1,2>::t.v, GH<1,2,1>::t.v,
  GH<1,2,2>::t.v, GH<1,2,3>::t.v, GH<1,3,2>::t.v, GH<1,3,3>::t.v, GH<1,3,4>::t.v,
  GH<1,4,3>::t.v, GH<1,4,4>::t.v,
  GH<2,0,2>::t.v, GH<2,1,1>::t.v, GH<2,1,2>::t.v, GH<2,1,3>::t.v, GH<2,2,0>::t.v,
  GH<2,2,1>::t.v, GH<2,2,2>::t.v, GH<2,2,3>::t.v, GH<2,2,4>::t.v, GH<2,3,1>::t.v,
  GH<2,3,2>::t.v, GH<2,3,3>::t.v, GH<2,3,4>::t.v, GH<2,4,2>::t.v, GH<2,4,3>::t.v,
  GH<2,4,4>::t.v
};

constexpr bool keep(float v){ return v > 1e-12f || v < -1e-12f; }

constexpr int count_nnz(){
  int n = 0;
  for (int p = 0; p < NPATHS; ++p){
    int l1 = PATHS_C[p].l1, l2 = PATHS_C[p].l2, l3 = PATHS_C[p].l3;
    int tot = (2*l1+1)*(2*l2+1)*(2*l3+1);
    for (int i = 0; i < tot; ++i) if (keep(G_PTRS[p][i])) ++n;
  }
  return n;
}
constexpr int NNZ = count_nnz();
static_assert(NNZ > 100 && NNZ < 4013, "unexpected CG sparsity");

constexpr int count_nnz_parity(int par){
  int n = 0;
  for (int p = 0; p < NPATHS; ++p){
    int l1 = PATHS_C[p].l1, l2 = PATHS_C[p].l2, l3 = PATHS_C[p].l3;
    if (((l1 + l2 + l3) & 1) != par) continue;
    int tot = (2*l1+1)*(2*l2+1)*(2*l3+1);
    for (int i = 0; i < tot; ++i) if (keep(G_PTRS[p][i])) ++n;
  }
  return n;
}
constexpr int NNZ_EVEN = count_nnz_parity(0);
constexpr int NNZ_ODD  = count_nnz_parity(1);
static_assert(NNZ_EVEN + NNZ_ODD == NNZ, "parity partition mismatch");

// Entry list, PARITY-MAJOR (all even-parity paths first, then odd), p ascending
// within each parity, a-major/b/c within each path. Per-slot accumulation order
// is therefore IDENTICAL to the plain path-major order (each output slot only
// ever receives contributions from a single parity class).
struct EntryList {
  short slot[NNZ];  // LOCAL slot within the parity half: l3^2 + c  (0..24)
  short ag[NNZ];    // l1^2 + a               (0..8)
  short bg[NNZ];    // l2^2 + b               (0..24)
  short p[NNZ];     // path index             (0..32)
  float val[NNZ];
};

constexpr EntryList make_entries(){
  EntryList E{};
  int n = 0;
  for (int par = 0; par < 2; ++par){
    for (int p = 0; p < NPATHS; ++p){
      const int l1 = PATHS_C[p].l1, l2 = PATHS_C[p].l2, l3 = PATHS_C[p].l3;
      if (((l1 + l2 + l3) & 1) != par) continue;
      const int NA = 2*l1+1, NB = 2*l2+1, NC = 2*l3+1;
      for (int a = 0; a < NA; ++a)
        for (int b = 0; b < NB; ++b)
          for (int c = 0; c < NC; ++c){
            const float v = G_PTRS[p][(a*NB + b)*NC + c];
            if (keep(v)){
              E.slot[n] = (short)(l3*l3 + c);
              E.ag[n]   = (short)(l1*l1 + a);
              E.bg[n]   = (short)(l2*l2 + b);
              E.p[n]    = (short)p;
              E.val[n]  = v;
              ++n;
            }
          }
    }
  }
  return E;
}
constexpr EntryList EN = make_entries();

} // namespace cgx

// ======================= device code =======================

// tpwf points at tp_weights + f; tpwf[p*16] is this lane's weight for path p.
// The (tpwf[p*16] * shr[ag]) products are CSE'd across entries sharing (p,ag);
// the identical-address tpw loads are CSE'd to one load per path PER HALF, so
// only ~16 weights are live at a time (vs 33 precomputed before).
template<int I>
__device__ __forceinline__ void apply_entry(float* __restrict__ acc, const float* __restrict__ shr,
                                            const float* __restrict__ yv, const float* __restrict__ tpwf){
  constexpr int   slot = cgx::EN.slot[I];
  constexpr int   ag   = cgx::EN.ag[I];
  constexpr int   bg   = cgx::EN.bg[I];
  constexpr int   p    = cgx::EN.p[I];
  constexpr float v    = cgx::EN.val[I];
  acc[slot] += v * ((tpwf[p * FDIM] * shr[ag]) * yv[bg]);
}

template<int BASE, std::size_t... Is>
__device__ __forceinline__ void apply_half(float* __restrict__ acc, const float* __restrict__ shr,
                                           const float* __restrict__ yv, const float* __restrict__ tpwf,
                                           std::index_sequence<Is...>){
  (apply_entry<BASE + (int)Is>(acc, shr, yv, tpwf), ...);
}

__global__ void __launch_bounds__(256)
BondCenteredTensorMomentDescriptor_62173946576949_kernel(
    const float* __restrict__ desc,   // (N_ATOMS, 1, 25, 16)
    const float* __restrict__ tpw,    // (33, 16)
    const float* __restrict__ disp,   // (E, 3)
    const int*   __restrict__ nidx,   // (E, 2)
    float* __restrict__ out)          // (E, 2, 25, 16)
{
  const int tid = blockIdx.x * 256 + threadIdx.x;
  const int f = tid & (FDIM - 1);
  const int e = tid >> 4;
  if (e >= N_EDGES) return;

  const int i0 = nidx[2*e + 0];
  const int i1 = nidx[2*e + 1];
  const float dx = disp[3*e + 0];
  const float dy = disp[3*e + 1];
  const float dz = disp[3*e + 2];

  const float r   = sqrtf(dx*dx + dy*dy + dz*dz);
  const float inv = 1.0f / fmaxf(r, 1e-9f);
  const float ux = dx*inv, uy = dy*inv, uz = dz*inv;

  // radial: sinc(k*r/CUTOFF), zeroed for r >= CUTOFF (k = f+1)
  const float xk = (float)(f + 1) * r * 0.2f;              // /CUTOFF=5
  const float px = 3.14159265358979323846f * xk;
  float rad = (px != 0.0f) ? (sinf(px) / px) : 1.0f;
  if (!(r < 5.0f)) rad = 0.0f;

  // real SH (l=0..2), reference ordering/constants, with rad FOLDED IN
  // (bond = rad * sh in the reference einsum operand 'a')
  float shr[9];
  shr[0] = rad * 0.28209479177387814f;
  shr[1] = rad * 0.4886025119029199f * uy;
  shr[2] = rad * 0.4886025119029199f * uz;
  shr[3] = rad * 0.4886025119029199f * ux;
  shr[4] = rad * 1.0925484305920792f * ux * uy;
  shr[5] = rad * 1.0925484305920792f * uy * uz;
  shr[6] = rad * 0.31539156525252005f * (3.0f * uz * uz - 1.0f);
  shr[7] = rad * 1.0925484305920792f * ux * uz;
  shr[8] = rad * 0.5f * 1.0925484305920792f * (ux*ux - uy*uy);

  // gather + sum the two atom descriptors (this thread's f column)
  const float* __restrict__ a0 = desc + (size_t)i0 * 400 + f;
  const float* __restrict__ a1 = desc + (size_t)i1 * 400 + f;
  float yv[25];
  #pragma unroll
  for (int b = 0; b < 25; ++b) yv[b] = a0[b * 16] + a1[b * 16];

  const float* __restrict__ tpwf = tpw + f;
  float* __restrict__ op = out + (size_t)e * 800 + f;

  // ---- pass 1: even-parity paths -> out[e][0][0..24][f] ----
  {
    float acc[25];
    #pragma unroll
    for (int i = 0; i < 25; ++i) acc[i] = 0.0f;
    apply_half<0>(acc, shr, yv, tpwf, std::make_index_sequence<cgx::NNZ_EVEN>{});
    #pragma unroll
    for (int s = 0; s < 25; ++s) op[s * 16] = acc[s];
  }

  // Pin the pass boundary: nothing from pass 2 may be hoisted above the pass-1
  // stores, so the 25 accumulator registers are provably dead and reusable.
  __builtin_amdgcn_sched_barrier(0);

  // ---- pass 2: odd-parity paths -> out[e][1][0..24][f] ----
  // Writes ALL 25 slots (slot c=0 / l3=0 odd parity is never touched by any
  // path -> stays 0.0f, required because d_out is poisoned with 0xAA before
  // every launch).
  {
    float acc[25];
    #pragma unroll
    for (int i = 0; i < 25; ++i) acc[i] = 0.0f;
    apply_half<cgx::NNZ_EVEN>(acc, shr, yv, tpwf, std::make_index_sequence<cgx::NNZ_ODD>{});
    #pragma unroll
    for (int s = 0; s < 25; ++s) op[400 + s * 16] = acc[s];
  }
}

extern "C" void kernel_launch(void* const* d_in, const int* in_sizes, int n_in,
                              void* d_out, int out_size, void* d_ws, size_t ws_size,
                              hipStream_t stream) {
  const float* desc = (const float*)d_in[0];   // atomic_descriptors
  const float* tpw  = (const float*)d_in[1];   // tp_weights (33,16)
  const float* disp = (const float*)d_in[2];   // neighbour_displacements
  const int*   nidx = (const int*)d_in[3];     // neighbour_indices
  float* out = (float*)d_out;

  const int total_threads = N_EDGES * FDIM;    // 800000
  const int block = 256;
  const int grid = (total_threads + block - 1) / block;  // 3125, exact

  BondCenteredTensorMomentDescriptor_62173946576949_kernel<<<grid, block, 0, stream>>>(
      desc, tpw, disp, nidx, out);
}